// Round 10
// baseline (615.946 us; speedup 1.0000x reference)
//
#include <hip/hip_runtime.h>

// ---------------- problem constants ----------------
#define B_    2
#define S_    1024
#define H_    1024
#define NH_   16
#define HD_   64
#define SE_   512
#define E_    1024
#define NEXP_ 8
#define FF_   2048
#define T_    (B_*S_)    // 2048 tokens
#define TE_   (B_*SE_)   // 1024 encoder tokens
#define PERM_MAX 6400    // 256-padded slots: <= 4096 + 8*255 = 6136
#define MAXRT 24         // 256-row tiles: sum ceil(c_e/256) <= 4096/256 + 8 = 24

typedef short v8s __attribute__((ext_vector_type(8)));
typedef short v4s __attribute__((ext_vector_type(4)));
typedef float v4f __attribute__((ext_vector_type(4)));
typedef _Float16 v8h __attribute__((ext_vector_type(8)));
typedef _Float16 v4h __attribute__((ext_vector_type(4)));

__device__ __forceinline__ unsigned short f2b(float f) {
  unsigned int u = __float_as_uint(f);
  u = (u + 0x7FFFu + ((u >> 16) & 1u)) >> 16;   // RNE f32 -> bf16 bits
  return (unsigned short)u;
}

// async global->LDS, 16 bytes/lane; lds base wave-uniform, global per-lane
__device__ __forceinline__ void g2l16(const void* g, void* l) {
  __builtin_amdgcn_global_load_lds(
      (const __attribute__((address_space(1))) unsigned int*)g,
      (__attribute__((address_space(3))) unsigned int*)l, 16, 0, 0);
}

// ---------------- int64-vs-int32 ABI detect ----------------
__global__ void detect_kern(const int* __restrict__ pos, const int* __restrict__ msk,
                            int* __restrict__ flags) {
  if (threadIdx.x == 0) {
    flags[0] = (pos[1] == 1) ? 0 : 1;
    flags[1] = (msk[1] == 1) ? 0 : 1;
  }
}

// ---------------- fused f32 -> fp16 hi/lo split (9 segments) ----------------
// segs 0-7: 1M f32 each (512 blocks); seg 8: enc 1M f32 (512 blocks) -> 4608
struct SplitArgs {
  const float* src[9];
  _Float16* dh[9];
  _Float16* dl[9];
};
__global__ __launch_bounds__(256)
void split_all(SplitArgs sa) {
  int b = blockIdx.x;
  int seg, i;
  if (b < 4096) { seg = b >> 9; i = (b & 511) * 256 + threadIdx.x; }
  else          { seg = 8;      i = (b - 4096) * 256 + threadIdx.x; }
  const float* x = sa.src[seg];
  v4f a = *(const v4f*)&x[i * 8];
  v4f c = *(const v4f*)&x[i * 8 + 4];
  v8h hv, lv;
  #pragma unroll
  for (int j = 0; j < 8; ++j) {
    float v = j < 4 ? a[j] : c[j - 4];
    _Float16 hh = (_Float16)v;
    hv[j] = hh; lv[j] = (_Float16)(v - (float)hh);
  }
  *(v8h*)&sa.dh[seg][i * 8] = hv;
  *(v8h*)&sa.dl[seg][i * 8] = lv;
}

// ---------------- fused f32 -> bf16 convert (MoE weights, 3 segments) -------
__global__ __launch_bounds__(256)
void cvt_all(const float* __restrict__ s0, const float* __restrict__ s1,
             const float* __restrict__ s2,
             unsigned short* __restrict__ d0, unsigned short* __restrict__ d1,
             unsigned short* __restrict__ d2) {
  int b = blockIdx.x;
  int seg = b >> 14;                 // 16384 blocks per segment
  int i = (b & 16383) * 256 + threadIdx.x;
  const float* x = seg == 0 ? s0 : (seg == 1 ? s1 : s2);
  unsigned short* y = seg == 0 ? d0 : (seg == 1 ? d1 : d2);
  v4f v = *(const v4f*)&x[i * 4];
  v4s o;
  #pragma unroll
  for (int j = 0; j < 4; ++j) o[j] = (short)f2b(v[j]);
  *(v4s*)&y[i * 4] = o;
}

// ---------------- RMSNorm f32 -> fp16 hi/lo ----------------
__global__ __launch_bounds__(256)
void rmsnorm_hl_kern(const float* __restrict__ x, const float* __restrict__ w,
                     _Float16* __restrict__ yh, _Float16* __restrict__ yl) {
  int row = blockIdx.x, tid = threadIdx.x;
  const float* xr = x + (long)row * 1024;
  v4f v = *(const v4f*)&xr[tid * 4];
  float ss = v[0]*v[0] + v[1]*v[1] + v[2]*v[2] + v[3]*v[3];
  #pragma unroll
  for (int off = 32; off; off >>= 1) ss += __shfl_xor(ss, off);
  __shared__ float sw[4];
  if ((tid & 63) == 0) sw[tid >> 6] = ss;
  __syncthreads();
  float tot = sw[0] + sw[1] + sw[2] + sw[3];
  float rs = rsqrtf(tot * (1.0f / 1024.0f) + 1e-6f);
  const float* wr = w + tid * 4;
  v4h oh, ol;
  #pragma unroll
  for (int j = 0; j < 4; ++j) {
    float f = v[j] * rs * wr[j];
    _Float16 hh = (_Float16)f;
    oh[j] = hh; ol[j] = (_Float16)(f - (float)hh);
  }
  *(v4h*)&yh[(long)row * 1024 + tid * 4] = oh;
  *(v4h*)&yl[(long)row * 1024 + tid * 4] = ol;
}

// ---------------- RMSNorm f32 -> bf16 (MoE h3) ----------------
__global__ __launch_bounds__(256)
void rmsnorm_kern(const float* __restrict__ x, const float* __restrict__ w,
                  unsigned short* __restrict__ y) {
  int row = blockIdx.x, tid = threadIdx.x;
  const float* xr = x + (long)row * 1024;
  v4f v = *(const v4f*)&xr[tid * 4];
  float ss = v[0]*v[0] + v[1]*v[1] + v[2]*v[2] + v[3]*v[3];
  #pragma unroll
  for (int off = 32; off; off >>= 1) ss += __shfl_xor(ss, off);
  __shared__ float sw[4];
  if ((tid & 63) == 0) sw[tid >> 6] = ss;
  __syncthreads();
  float tot = sw[0] + sw[1] + sw[2] + sw[3];
  float rs = rsqrtf(tot * (1.0f / 1024.0f) + 1e-6f);
  const float* wr = w + tid * 4;
  v4s o;
  #pragma unroll
  for (int j = 0; j < 4; ++j) o[j] = (short)f2b(v[j] * rs * wr[j]);
  *(v4s*)&y[(long)row * 1024 + tid * 4] = o;
}

// ---------------- RoPE: q f32 in-place; k rotated -> fp16 hi/lo ----------
__global__ __launch_bounds__(256)
void rope_split_kern(float* __restrict__ q, const float* __restrict__ k,
                     _Float16* __restrict__ kh, _Float16* __restrict__ kl,
                     const int* __restrict__ pos, const int* __restrict__ flags) {
  int g = blockIdx.x * 256 + threadIdx.x;
  int d = g & 31;
  int h = (g >> 5) & 15;
  int s = (g >> 9) & (S_ - 1);
  int b = g >> 19;
  long base = (((long)(b * S_ + s)) * NH_ + h) * HD_;
  int pidx = b * S_ + s;
  int pv = pos[flags[0] ? (pidx << 1) : pidx];
  float p = (float)pv;
  float inv = powf(10000.0f, -(float)d * (1.0f / 32.0f));
  float f = p * inv;
  float sn = sinf(f), cs = cosf(f);
  float q1 = q[base + d], q2 = q[base + d + 32];
  q[base + d]      = q1 * cs - q2 * sn;
  q[base + d + 32] = q2 * cs + q1 * sn;
  float k1 = k[base + d], k2 = k[base + d + 32];
  float kr1 = k1 * cs - k2 * sn;
  float kr2 = k2 * cs + k1 * sn;
  _Float16 hh = (_Float16)kr1;
  kh[base + d] = hh; kl[base + d] = (_Float16)(kr1 - (float)hh);
  hh = (_Float16)kr2;
  kh[base + d + 32] = hh; kl[base + d + 32] = (_Float16)(kr2 - (float)hh);
}

// ---------------- V transpose + split: [B,Sk,NH,64]f32 -> [B,NH,64,Sk]f16 x2
__global__ __launch_bounds__(256)
void vtrans_kern(const float* __restrict__ vf, _Float16* __restrict__ vth,
                 _Float16* __restrict__ vtl, int Sk) {
  int kb = blockIdx.x, bh = blockIdx.y;
  int b = bh >> 4, h = bh & 15;
  int t = threadIdx.x;
  __shared__ float tile[64][65];
  int key = t >> 2, dsub = (t & 3) * 16;
  const float* src = vf + (((long)(b * Sk + kb * 64 + key)) * NH_ + h) * HD_ + dsub;
  #pragma unroll
  for (int j = 0; j < 16; j += 4) *(v4f*)&tile[key][dsub + j] = *(const v4f*)&src[j];
  __syncthreads();
  int d = t >> 2, ksub = (t & 3) * 16;
  v8h hv0, lv0, hv1, lv1;
  #pragma unroll
  for (int j = 0; j < 16; ++j) {
    float v = tile[ksub + j][d];
    _Float16 hh = (_Float16)v;
    if (j < 8) { hv0[j] = hh; lv0[j] = (_Float16)(v - (float)hh); }
    else       { hv1[j - 8] = hh; lv1[j - 8] = (_Float16)(v - (float)hh); }
  }
  long ob = (((long)(b * NH_ + h)) * HD_ + d) * Sk + kb * 64 + ksub;
  *(v8h*)&vth[ob] = hv0; *(v8h*)&vth[ob + 8] = hv1;
  *(v8h*)&vtl[ob] = lv0; *(v8h*)&vtl[ob + 8] = lv1;
}

// ---------------- split-fp16 3-pass GEMM, 128x64 tile, XCD-swizzled ---------
// T4 pipeline: 3 LDS buffers, depth-2 prefetch, counted s_waitcnt vmcnt(N)
// + raw s_barrier. Per wave per stage: 6 gload_lds -> steady-state 12 in
// flight; vmcnt(6) drains only the stage being consumed. Never vmcnt(0)
// in the main loop (last iter only).
struct ZArg {
  const _Float16 *Ah, *Al, *Bh, *Bl;
  const float *bias, *resid;
  float *Cf;
  _Float16 *Ch, *Cl;
  int M;
};

__global__ __launch_bounds__(256)
void gemm_hl(ZArg z0, ZArg z1, ZArg z2, int K) {
  ZArg za = blockIdx.z == 0 ? z0 : (blockIdx.z == 1 ? z1 : z2);
  int flat = blockIdx.x;                       // 256 per z
  int wg = (flat & 7) * 32 + (flat >> 3);      // XCD swizzle (256 = 8*32)
  int row0 = (wg >> 4) * 128;
  int col0 = (wg & 15) * 64;
  if (row0 >= za.M) return;
  int tid = threadIdx.x, lane = tid & 63, w = tid >> 6;
  int lr = lane & 15, lg = lane >> 4;
  int wr = w >> 1, wc = w & 1;
  int rsw = (lr >> 1) & 3;           // read-side swizzle

  __shared__ _Float16 Ah_s[3][128 * 32], Al_s[3][128 * 32];   // 48 KB
  __shared__ _Float16 Bh_s[3][64 * 32], Bl_s[3][64 * 32];     // 24 KB

  int av0 = w * 64 + lane, av1 = (w + 4) * 64 + lane;
  int ar0 = av0 >> 2, as0 = (av0 & 3) ^ ((ar0 >> 1) & 3);
  int ar1 = av1 >> 2, as1 = (av1 & 3) ^ ((ar1 >> 1) & 3);
  int bv = w * 64 + lane;
  int br = bv >> 2, bs = (bv & 3) ^ ((br >> 1) & 3);
  const _Float16* ga0h = za.Ah + (long)(row0 + ar0) * K + as0 * 8;
  const _Float16* ga0l = za.Al + (long)(row0 + ar0) * K + as0 * 8;
  const _Float16* ga1h = za.Ah + (long)(row0 + ar1) * K + as1 * 8;
  const _Float16* ga1l = za.Al + (long)(row0 + ar1) * K + as1 * 8;
  const _Float16* gbh  = za.Bh + (long)(col0 + br) * K + bs * 8;
  const _Float16* gbl  = za.Bl + (long)(col0 + br) * K + bs * 8;

  auto stage = [&](int buf, int k0) {
    g2l16(ga0h + k0, (char*)Ah_s[buf] + w * 1024);
    g2l16(ga1h + k0, (char*)Ah_s[buf] + (w + 4) * 1024);
    g2l16(ga0l + k0, (char*)Al_s[buf] + w * 1024);
    g2l16(ga1l + k0, (char*)Al_s[buf] + (w + 4) * 1024);
    g2l16(gbh + k0, (char*)Bh_s[buf] + w * 1024);
    g2l16(gbl + k0, (char*)Bl_s[buf] + w * 1024);
  };

  v4f acc[4][2] = {};
  int nk = K >> 5;
  stage(0, 0);
  stage(1, 32);

  for (int it = 0; it < nk; ++it) {
    if (it == nk - 1) asm volatile("s_waitcnt vmcnt(0)" ::: "memory");
    else              asm volatile("s_waitcnt vmcnt(6)" ::: "memory");
    __builtin_amdgcn_s_barrier();
    asm volatile("" ::: "memory");
    if (it + 2 < nk) stage((it + 2) % 3, (it + 2) << 5);
    int cur = it % 3;

    v8h ah[4], al[4], bh[2], bl[2];
    #pragma unroll
    for (int m = 0; m < 4; ++m) {
      int off = (wr * 64 + m * 16 + lr) * 64 + ((lg ^ rsw) << 4);
      ah[m] = *(const v8h*)((char*)Ah_s[cur] + off);
      al[m] = *(const v8h*)((char*)Al_s[cur] + off);
    }
    #pragma unroll
    for (int n = 0; n < 2; ++n) {
      int off = (wc * 32 + n * 16 + lr) * 64 + ((lg ^ rsw) << 4);
      bh[n] = *(const v8h*)((char*)Bh_s[cur] + off);
      bl[n] = *(const v8h*)((char*)Bl_s[cur] + off);
    }
    #pragma unroll
    for (int m = 0; m < 4; ++m)
      #pragma unroll
      for (int n = 0; n < 2; ++n) {
        acc[m][n] = __builtin_amdgcn_mfma_f32_16x16x32_f16(ah[m], bh[n], acc[m][n], 0, 0, 0);
        acc[m][n] = __builtin_amdgcn_mfma_f32_16x16x32_f16(ah[m], bl[n], acc[m][n], 0, 0, 0);
        acc[m][n] = __builtin_amdgcn_mfma_f32_16x16x32_f16(al[m], bh[n], acc[m][n], 0, 0, 0);
      }
  }

  #pragma unroll
  for (int m = 0; m < 4; ++m) {
    int rbase = row0 + wr * 64 + m * 16 + lg * 4;
    #pragma unroll
    for (int n = 0; n < 2; ++n) {
      int gcol = col0 + wc * 32 + n * 16 + lr;
      float bb = za.bias ? za.bias[gcol] : 0.0f;
      #pragma unroll
      for (int rr = 0; rr < 4; ++rr) {
        long idx = (long)(rbase + rr) * 1024 + gcol;
        float v = acc[m][n][rr] + bb;
        if (za.Cf) {
          za.Cf[idx] = za.resid ? (za.resid[idx] + v) : v;
        } else {
          _Float16 hh = (_Float16)v;
          za.Ch[idx] = hh;
          za.Cl[idx] = (_Float16)(v - (float)hh);
        }
      }
    }
  }
}

// ---------------- flash attention: pre-split K/V^T, gload_lds staging --------
template<bool CAUSAL>
__global__ __launch_bounds__(256)
void attn_hl(const float* __restrict__ Q,
             const _Float16* __restrict__ Khg, const _Float16* __restrict__ Klg,
             const _Float16* __restrict__ Vhg, const _Float16* __restrict__ Vlg,
             _Float16* __restrict__ Oh, _Float16* __restrict__ Ol,
             const int* __restrict__ mask, const int* __restrict__ flags,
             int Sq, int Sk, float qscale) {
  int qt = blockIdx.x, bh = blockIdx.y;
  int b = bh >> 4, h = bh & 15;
  int tid = threadIdx.x, lane = tid & 63, w = tid >> 6;
  int lr = lane & 15, lg = lane >> 4;
  int q0 = qt * 64;
  int mf = (!CAUSAL && mask) ? flags[1] : 0;
  int swz = lr & 7;

  __shared__ _Float16 Kh_s[64 * 64], Kl_s[64 * 64];
  __shared__ _Float16 Vh_s[64 * 64], Vl_s[64 * 64];
  __shared__ _Float16 Psh[4][16][72], Psl[4][16][72];

  v8h qh[2], ql[2];
  {
    long qbase = ((long)(b * Sq + q0 + w * 16 + lr) * NH_ + h) * HD_;
    #pragma unroll
    for (int kk = 0; kk < 2; ++kk) {
      v4f f0 = *(const v4f*)&Q[qbase + kk * 32 + lg * 8];
      v4f f1 = *(const v4f*)&Q[qbase + kk * 32 + lg * 8 + 4];
      #pragma unroll
      for (int j = 0; j < 8; ++j) {
        float f = (j < 4 ? f0[j] : f1[j - 4]) * qscale;
        _Float16 hh = (_Float16)f;
        qh[kk][j] = hh;
        ql[kk][j] = (_Float16)(f - (float)hh);
      }
    }
  }
  v4f of[4] = {};
  float m4[4], l4[4];
  #pragma unroll
  for (int i = 0; i < 4; ++i) { m4[i] = -3e38f; l4[i] = 0.0f; }

  int nkt = CAUSAL ? (qt + 1) : (Sk >> 6);
  for (int kt = 0; kt < nkt; ++kt) {
    __syncthreads();
    #pragma unroll
    for (int i = 0; i < 2; ++i) {
      int c = w + i * 4;
      int v = c * 64 + lane;
      int row = v >> 3, c8 = v & 7;
      int sc = (c8 ^ (row & 7)) << 3;
      long kb = ((long)(b * Sk + kt * 64 + row) * NH_ + h) * HD_ + sc;
      g2l16(Khg + kb, (char*)Kh_s + c * 1024);
      g2l16(Klg + kb, (char*)Kl_s + c * 1024);
      long vb = ((long)(b * NH_ + h) * HD_ + row) * Sk + kt * 64 + sc;
      g2l16(Vhg + vb, (char*)Vh_s + c * 1024);
      g2l16(Vlg + vb, (char*)Vl_s + c * 1024);
    }
    __syncthreads();

    v4f sf[4] = {};
    #pragma unroll
    for (int kk = 0; kk < 2; ++kk)
      #pragma unroll
      for (int n = 0; n < 4; ++n) {
        int off = (n * 16 + lr) * 128 + ((((kk << 2) | lg) ^ swz) << 4);
        v8h kbh = *(const v8h*)((char*)Kh_s + off);
        v8h kbl = *(const v8h*)((char*)Kl_s + off);
        sf[n] = __builtin_amdgcn_mfma_f32_16x16x32_f16(qh[kk], kbh, sf[n], 0, 0, 0);
        sf[n] = __builtin_amdgcn_mfma_f32_16x16x32_f16(qh[kk], kbl, sf[n], 0, 0, 0);
        sf[n] = __builtin_amdgcn_mfma_f32_16x16x32_f16(ql[kk], kbh, sf[n], 0, 0, 0);
      }

    if constexpr (CAUSAL) {
      if (kt == qt) {
        #pragma unroll
        for (int n = 0; n < 4; ++n) {
          int kcol = kt * 64 + n * 16 + lr;
          #pragma unroll
          for (int rr = 0; rr < 4; ++rr) {
            int qr = q0 + w * 16 + lg * 4 + rr;
            if (kcol > qr) sf[n][rr] = -1e9f;
          }
        }
      }
    } else {
      if (mask) {
        #pragma unroll
        for (int n = 0; n < 4; ++n) {
          int kcol = kt * 64 + n * 16 + lr;
          int mi = b * Sk + kcol;
          if (mask[mf ? (mi << 1) : mi] == 0) {
            #pragma unroll
            for (int rr = 0; rr < 4; ++rr) sf[n][rr] = -1e9f;
          }
        }
      }
    }

    float al[4];
    #pragma unroll
    for (int rr = 0; rr < 4; ++rr) {
      float mx = fmaxf(fmaxf(sf[0][rr], sf[1][rr]), fmaxf(sf[2][rr], sf[3][rr]));
      #pragma unroll
      for (int off = 8; off; off >>= 1) mx = fmaxf(mx, __shfl_xor(mx, off));
      float mn = fmaxf(m4[rr], mx);
      al[rr] = __expf(m4[rr] - mn);
      m4[rr] = mn;
      float rs = 0.0f;
      #pragma unroll
      for (int n = 0; n < 4; ++n) {
        float pv = __expf(sf[n][rr] - mn);
        sf[n][rr] = pv;
        rs += pv;
      }
      #pragma unroll
      for (int off = 8; off; off >>= 1) rs += __shfl_xor(rs, off);
      l4[rr] = l4[rr] * al[rr] + rs;
    }

    #pragma unroll
    for (int n = 0; n < 4; ++n)
      #pragma unroll
      for (int rr = 0; rr < 4; ++rr) {
        of[n][rr] *= al[rr];
        float pv = sf[n][rr];
        _Float16 ph = (_Float16)pv;
        Psh[w][lg * 4 + rr][n * 16 + lr] = ph;
        Psl[w][lg * 4 + rr][n * 16 + lr] = (_Float16)(pv - (float)ph);
      }
    __syncthreads();

    #pragma unroll
    for (int kc = 0; kc < 2; ++kc) {
      v8h pah = *(const v8h*)&Psh[w][lr][kc * 32 + lg * 8];
      v8h pal = *(const v8h*)&Psl[w][lr][kc * 32 + lg * 8];
      #pragma unroll
      for (int n = 0; n < 4; ++n) {
        int off = (n * 16 + lr) * 128 + ((((kc << 2) | lg) ^ swz) << 4);
        v8h vbh = *(const v8h*)((char*)Vh_s + off);
        v8h vbl = *(const v8h*)((char*)Vl_s + off);
        of[n] = __builtin_amdgcn_mfma_f32_16x16x32_f16(pah, vbh, of[n], 0, 0, 0);
        of[n] = __builtin_amdgcn_mfma_f32_16x16x32_f16(pah, vbl, of[n], 0, 0, 0);
        of[n] = __builtin_amdgcn_mfma_f32_16x16x32_f16(pal, vbh, of[n], 0, 0, 0);
      }
    }
  }

  #pragma unroll
  for (int rr = 0; rr < 4; ++rr) {
    int qr = q0 + w * 16 + lg * 4 + rr;
    float inv = 1.0f / l4[rr];
    long ob = (long)(b * Sq + qr) * 1024 + h * 64;
    #pragma unroll
    for (int n = 0; n < 4; ++n) {
      float v = of[n][rr] * inv;
      _Float16 hh = (_Float16)v;
      Oh[ob + n * 16 + lr] = hh;
      Ol[ob + n * 16 + lr] = (_Float16)(v - (float)hh);
    }
  }
}

// ---------------- MoE GEMM1: 256x64 tile, 8 waves, dual-B, T4 pipe, XCD-swz -
__global__ __launch_bounds__(512)
void moe_gemm1(const unsigned short* __restrict__ A,
               const unsigned short* __restrict__ B1,
               const unsigned short* __restrict__ B2,
               unsigned short* __restrict__ Cb,
               const int* __restrict__ tm_e, const int* __restrict__ tm_slot,
               const int* __restrict__ ntl, const int* __restrict__ perm) {
  int flat = blockIdx.x;                        // 768 = 8*96
  int wg = (flat & 7) * 96 + (flat >> 3);       // XCD swizzle
  int tile = wg >> 5;
  if (tile >= ntl[0]) return;
  int col0 = (wg & 31) * 64;
  int e = tm_e[tile];
  int row0 = tm_slot[tile];
  const unsigned short* Bp1 = B1 + (long)e * (FF_ * H_);
  const unsigned short* Bp2 = B2 + (long)e * (FF_ * H_);
  int tid = threadIdx.x, lane = tid & 63, w = tid >> 6;   // 8 waves
  int lr = lane & 15, lg = lane >> 4;
  int wr = w >> 1, wc = w & 1;
  int rsw = (lr >> 1) & 3;

  __shared__ unsigned short As[3][256 * 32];    // 48 KB
  __shared__ unsigned short Bs1[3][64 * 32];    // 12 KB
  __shared__ unsigned short Bs2[3][64 * 32];    // 12 KB

  const unsigned short* ga[2];
  #pragma unroll
  for (int i = 0; i < 2; ++i) {
    int c = i * 512 + tid;
    int r = c >> 2, sub = (c & 3) ^ ((r >> 1) & 3);
    int tok = perm[row0 + r];
    ga[i] = A + (long)(tok < 0 ? 0 : tok) * H_ + sub * 8;
  }
  int bc = tid & 255;
  int rb = bc >> 2, sb = (bc & 3) ^ ((rb >> 1) & 3);
  const unsigned short* gB = (tid < 256 ? Bp1 : Bp2) + (long)(col0 + rb) * H_ + sb * 8;
  size_t lBoff = (size_t)((w & 3) * 64) * 8;

  auto stage = [&](int buf, int k0) {
    #pragma unroll
    for (int i = 0; i < 2; ++i)
      g2l16(ga[i] + k0, As[buf] + (size_t)(i * 512 + w * 64) * 8);
    g2l16(gB + k0, (tid < 256 ? Bs1[buf] : Bs2[buf]) + lBoff);
  };

  v4f acc[4][2] = {};
  v4f acc2[4][2] = {};
  const int nk = 32;                            // K = 1024
  stage(0, 0);
  stage(1, 32);

  for (int it = 0; it < nk; ++it) {
    if (it == nk - 1) asm volatile("s_waitcnt vmcnt(0)" ::: "memory");
    else              asm volatile("s_waitcnt vmcnt(3)" ::: "memory");
    __builtin_amdgcn_s_barrier();
    asm volatile("" ::: "memory");
    if (it + 2 < nk) stage((it + 2) % 3, (it + 2) << 5);
    int cur = it % 3;

    v8s a[4], b1[2], b2[2];
    #pragma unroll
    for (int m = 0; m < 4; ++m)
      a[m] = *(const v8s*)&As[cur][(wr * 64 + m * 16 + lr) * 32 + (lg ^ rsw) * 8];
    #pragma unroll
    for (int n = 0; n < 2; ++n) {
      b1[n] = *(const v8s*)&Bs1[cur][(wc * 32 + n * 16 + lr) * 32 + (lg ^ rsw) * 8];
      b2[n] = *(const v8s*)&Bs2[cur][(wc * 32 + n * 16 + lr) * 32 + (lg ^ rsw) * 8];
    }
    #pragma unroll
    for (int m = 0; m < 4; ++m)
      #pragma unroll
      for (int n = 0; n < 2; ++n) {
        acc[m][n]  = __builtin_amdgcn_mfma_f32_16x16x32_bf16(a[m], b1[n], acc[m][n], 0, 0, 0);
        acc2[m][n] = __builtin_amdgcn_mfma_f32_16x16x32_bf16(a[m], b2[n], acc2[m][n], 0, 0, 0);
      }
  }

  #pragma unroll
  for (int m = 0; m < 4; ++m) {
    int grow = row0 + wr * 64 + m * 16 + lg * 4;
    #pragma unroll
    for (int n = 0; n < 2; ++n) {
      int gcol = col0 + wc * 32 + n * 16 + lr;
      #pragma unroll
      for (int rr = 0; rr < 4; ++rr) {
        float v = acc[m][n][rr];
        float g = v / (1.0f + __expf(-v));
        Cb[(long)(grow + rr) * FF_ + gcol] = f2b(g * acc2[m][n][rr]);
      }
    }
  }
}

// ---------------- MoE GEMM2: 128x64 tile, 4 waves, T4 pipe, scatter ---------
__global__ __launch_bounds__(256)
void moe_gemm2(const unsigned short* __restrict__ A,
               const unsigned short* __restrict__ B,
               float* __restrict__ Cf,
               const int* __restrict__ tm_e, const int* __restrict__ tm_slot,
               const int* __restrict__ ntl,
               const int* __restrict__ perm, const float* __restrict__ pwgt) {
  int flat = blockIdx.x;                        // 768 = 8*96
  int wg = (flat & 7) * 96 + (flat >> 3);       // XCD swizzle
  int t2 = wg >> 4;                             // 0..47 (128-row sub-tiles)
  int tile = t2 >> 1;
  if (tile >= ntl[0]) return;
  int row0 = tm_slot[tile] + (t2 & 1) * 128;
  int col0 = (wg & 15) * 64;
  int e = tm_e[tile];
  const unsigned short* Bp = B + (long)e * (H_ * FF_);
  int tid = threadIdx.x, lane = tid & 63, w = tid >> 6;   // 4 waves
  int lr = lane & 15, lg = lane >> 4;
  int rsw = (lr >> 1) & 3;

  __shared__ unsigned short As[3][128 * 32];    // 24 KB
  __shared__ unsigned short Bs[3][64 * 32];     // 12 KB

  const unsigned short* ga[2];
  #pragma unroll
  for (int i = 0; i < 2; ++i) {
    int c = i * 256 + tid;
    int r = c >> 2, sub = (c & 3) ^ ((r >> 1) & 3);
    ga[i] = A + (long)(row0 + r) * FF_ + sub * 8;
  }
  int rb = tid >> 2, sb = (tid & 3) ^ ((rb >> 1) & 3);
  const unsigned short* gb = Bp + (long)(col0 + rb) * FF_ + sb * 8;

  auto stage = [&](int buf, int k0) {
    #pragma unroll
    for (int i = 0; i < 2; ++i)
      g2l16(ga[i] + k0, As[buf] + (size_t)(i * 256 + w * 64) * 8);
    g2l16(gb + k0, Bs[buf] + (size_t)(w * 64) * 8);
  };

  // wave w owns rows [w*32, w*32+32), all 64 cols: acc[2][4]
  v4f acc[2][4] = {};
  const int nk = 64;                            // K = 2048
  stage(0, 0);
  stage(1, 32);

  for (int it = 0; it < nk; ++it) {
    if (it == nk - 1) asm volatile("s_waitcnt vmcnt(0)" ::: "memory");
    else              asm volatile("s_waitcnt vmcnt(3)" ::: "memory");
    __builtin_amdgcn_s_barrier();
    asm volatile("" ::: "memory");
    if (it + 2 < nk) stage((it + 2) % 3, (it + 2) << 5);
    int cur = it % 3;

    v8s a[2], b[4];
    #pragma unroll
    for (int m = 0; m < 2; ++m)
      a[m] = *(const v8s*)&As[cur][(w * 32 + m * 16 + lr) * 32 + (lg ^ rsw) * 8];
    #pragma unroll
    for (int n = 0; n < 4; ++n)
      b[n] = *(const v8s*)&Bs[cur][(n * 16 + lr) * 32 + (lg ^ rsw) * 8];
    #pragma unroll
    for (int m = 0; m < 2; ++m)
      #pragma unroll
      for (int n = 0; n < 4; ++n)
        acc[m][n] = __builtin_amdgcn_mfma_f32_16x16x32_bf16(a[m], b[n], acc[m][n], 0, 0, 0);
  }

  #pragma unroll
  for (int m = 0; m < 2; ++m) {
    int grow = row0 + w * 32 + m * 16 + lg * 4;
    #pragma unroll
    for (int rr = 0; rr < 4; ++rr) {
      int tok = perm[grow + rr];
      if (tok < 0) continue;
      float pw = pwgt[grow + rr];
      #pragma unroll
      for (int n = 0; n < 4; ++n) {
        int gcol = col0 + n * 16 + lr;
        atomicAdd(&Cf[(long)tok * H_ + gcol], acc[m][n][rr] * pw);
      }
    }
  }
}

// ---------------- MoE router: f32 rms + logits + top-2 ----------------
__global__ __launch_bounds__(64)
void router_kern(const float* __restrict__ x, const float* __restrict__ w,
                 const float* __restrict__ gw,
                 int* __restrict__ topi, float* __restrict__ topw,
                 int* __restrict__ counts) {
  int t = blockIdx.x, lane = threadIdx.x;
  const float* xr = x + (long)t * 1024;
  float vals[16];
  float ss = 0.0f;
  #pragma unroll
  for (int i = 0; i < 16; ++i) { float v = xr[lane + i * 64]; vals[i] = v; ss += v * v; }
  #pragma unroll
  for (int off = 32; off; off >>= 1) ss += __shfl_xor(ss, off);
  float rs = rsqrtf(ss * (1.0f / 1024.0f) + 1e-6f);
  #pragma unroll
  for (int i = 0; i < 16; ++i) vals[i] *= rs * w[lane + i * 64];
  float lgts[8];
  #pragma unroll
  for (int e = 0; e < 8; ++e) {
    const float* g = gw + e * 1024;
    float s = 0.0f;
    #pragma unroll
    for (int i = 0; i < 16; ++i) s += vals[i] * g[lane + i * 64];
    #pragma unroll
    for (int off = 32; off; off >>= 1) s += __shfl_xor(s, off);
    lgts[e] = s;
  }
  int i1 = 0; float l1 = lgts[0];
  #pragma unroll
  for (int e = 1; e < 8; ++e) if (lgts[e] > l1) { l1 = lgts[e]; i1 = e; }
  int i2 = -1; float l2 = -3e38f;
  #pragma unroll
  for (int e = 0; e < 8; ++e) if (e != i1 && lgts[e] > l2) { l2 = lgts[e]; i2 = e; }
  float w1 = 1.0f / (1.0f + __expf(l2 - l1));
  if (lane == 0) {
    topi[t * 2] = i1; topi[t * 2 + 1] = i2;
    topw[t * 2] = w1; topw[t * 2 + 1] = 1.0f - w1;
    atomicAdd(&counts[i1], 1);
    atomicAdd(&counts[i2], 1);
  }
}

// ---------------- MoE finalize: 256-padded offsets + tile map ----------------
__global__ __launch_bounds__(256)
void finalize_kern(const int* __restrict__ counts, int* __restrict__ poff,
                   int* __restrict__ tm_e, int* __restrict__ tm_slot,
                   int* __restrict__ ntl, int* __restrict__ perm) {
  __shared__ int stot;
  if (threadIdx.x == 0) {
    int off = 0, nt = 0;
    for (int e = 0; e < 8; ++e) {
      poff[e] = off;
      int c = counts[e];
      int ntE = (c + 255) >> 8;
      for (int i = 0; i < ntE; ++i) { tm_e[nt] = e; tm_slot[nt] = off + i * 256; ++nt; }
      off += ntE * 256;
    }
    ntl[0] = nt; ntl[1] = off;
    stot = off;
  }
  __syncthreads();
  for (int s = threadIdx.x; s < stot; s += 256) perm[s] = -1;
}

__global__ __launch_bounds__(256)
void scatter_kern(const int* __restrict__ topi, const float* __restrict__ topw,
                  const int* __restrict__ poff, int* __restrict__ cursor,
                  int* __restrict__ perm, float* __restrict__ pwgt) {
  int t = blockIdx.x * 256 + threadIdx.x;
  if (t >= T_) return;
  #pragma unroll
  for (int kk = 0; kk < 2; ++kk) {
    int e = topi[t * 2 + kk];
    int pos = atomicAdd(&cursor[e], 1);
    int slot = poff[e] + pos;
    perm[slot] = t;
    pwgt[slot] = topw[t * 2 + kk];
  }
}

// ---------------- host launcher ----------------
extern "C" void kernel_launch(void* const* d_in, const int* in_sizes, int n_in,
                              void* d_out, int out_size, void* d_ws, size_t ws_size,
                              hipStream_t stream) {
  (void)in_sizes; (void)n_in; (void)out_size; (void)ws_size;
  const float* x_in  = (const float*)d_in[0];
  const int*  posids = (const int*)d_in[1];
  const float* enc   = (const float*)d_in[2];
  const int*  emask  = (const int*)d_in[3];
  const float* inln  = (const float*)d_in[4];
  const float* wq    = (const float*)d_in[5];
  const float* wk    = (const float*)d_in[6];
  const float* wv    = (const float*)d_in[7];
  const float* wo    = (const float*)d_in[8];
  const float* cnorm = (const float*)d_in[9];
  const float* cqw   = (const float*)d_in[10];
  const float* cqb   = (const float*)d_in[11];
  const float* ckw   = (const float*)d_in[12];
  const float* ckb   = (const float*)d_in[13];
  const float* cvw   = (const float*)d_in[14];
  const float* cvb   = (const float*)d_in[15];
  const float* cow   = (const float*)d_in[16];
  const float* cob   = (const float*)d_in[17];
  const float* pln   = (const float*)d_in[18];
  const float* gatew = (const float*)d_in[19];
  const float* w1    = (const float*)d_in[20];
  const float* w2    = (const float*)d_in[21];
  const float* w3    = (const float*)d_in[22];
  float* out = (float*)d_out;

  char* p = (char*)d_ws;
  auto alloc = [&](size_t bytes) -> char* {
    char* r = p;
    p += (bytes + 255) & ~(size_t)255;
    return r;
  };
  const size_t MB = 1024 * 1024;
  char* A1 = alloc(4 * MB);   // hh -> oh -> ckh
  char* A2 = alloc(4 * MB);   // hl -> ol -> ckl
  char* Bq = alloc(8 * MB);   // qf -> cqf -> ffh
  char* Bk = alloc(8 * MB);   // kf -> cvth/cvtl -> ffh
  char* Bv = alloc(8 * MB);   // vf -> cvf -> ffh
  char* C1 = alloc(4 * MB);   // kh -> h2h -> ffh tail (dead by MoE)
  char* C2 = alloc(4 * MB);   // kl -> h2l
  char* D1 = alloc(4 * MB);   // vth -> coh
  char* D2 = alloc(4 * MB);   // vtl -> col
  float* x1 = (float*)alloc(8 * MB);
  float* x2 = (float*)alloc(8 * MB);
  unsigned short* h3b = (unsigned short*)alloc(4 * MB);
  _Float16* ench = (_Float16*)alloc(2 * MB);
  _Float16* encl = (_Float16*)alloc(2 * MB);
  int*   meta    = (int*)alloc(4 * (8 + 8 + 8 + 2 + 2 + MAXRT + MAXRT));
  int*   counts  = meta;
  int*   cursor  = meta + 8;
  int*   poff    = meta + 16;
  int*   ntl     = meta + 24;
  int*   flags   = meta + 26;
  int*   tm_e    = meta + 28;
  int*   tm_slot = meta + 28 + MAXRT;
  int*   topi    = (int*)alloc((size_t)T_ * 2 * 4);
  float* topw    = (float*)alloc((size_t)T_ * 2 * 4);
  int*   perm    = (int*)alloc((size_t)PERM_MAX * 4);
  float* pwgt    = (float*)alloc((size_t)PERM_MAX * 4);
  unsigned short* w1b = (unsigned short*)alloc((size_t)NEXP_ * FF_ * H_ * 2);  // 32 MB, also wsp
  unsigned short* w3b = (unsigned short*)alloc((size_t)NEXP_ * FF_ * H_ * 2);
  unsigned short* w2b = (unsigned short*)alloc((size_t)NEXP_ * H_ * FF_ * 2);

  // aliased views
  _Float16 *hh = (_Float16*)A1, *hl = (_Float16*)A2;
  _Float16 *oh = (_Float16*)A1, *ol = (_Float16*)A2;
  _Float16 *ckh = (_Float16*)A1, *ckl = (_Float16*)A2;
  float* qf = (float*)Bq;  float* cqf = (float*)Bq;
  float* kf = (float*)Bk;
  _Float16 *cvth = (_Float16*)Bk, *cvtl = (_Float16*)(Bk + 4 * MB);
  float* vf = (float*)Bv;  float* cvf = (float*)Bv;
  _Float16 *kh = (_Float16*)C1, *kl = (_Float16*)C2;
  _Float16 *h2h = (_Float16*)C1, *h2l = (_Float16*)C2;
  _Float16 *vth = (_Float16*)D1, *vtl = (_Float16*)D2;
  _Float16 *coh = (_Float16*)D1, *col = (_Float16*)D2;
  unsigned short* ffh = (unsigned short*)Bq;   // spans Bq..Bv + C1 (28MB > 25.1)
  _Float16* wsp = (_Float16*)w1b;              // split weights until MoE cvt
  auto wsph = [&](int i) { return wsp + (size_t)i * 2097152; };
  auto wspl = [&](int i) { return wsp + (size_t)i * 2097152 + 1048576; };

  dim3 blk(256);

  detect_kern<<<1, 64, 0, stream>>>(posids, emask, flags);

  // fused pre-split of 8 attention weights + encoder states (4096+512 blocks)
  {
    SplitArgs sa;
    const float* wlist[8] = {wq, wk, wv, wo, cqw, ckw, cvw, cow};
    for (int i = 0; i < 8; ++i) { sa.src[i] = wlist[i]; sa.dh[i] = wsph(i); sa.dl[i] = wspl(i); }
    sa.src[8] = enc; sa.dh[8] = ench; sa.dl[8] = encl;
    split_all<<<4608, blk, 0, stream>>>(sa);
  }

  // ---- self-attention block ----
  rmsnorm_hl_kern<<<T_, blk, 0, stream>>>(x_in, inln, hh, hl);
  {
    ZArg zq = {hh, hl, wsph(0), wspl(0), nullptr, nullptr, qf, nullptr, nullptr, 2048};
    ZArg zk = {hh, hl, wsph(1), wspl(1), nullptr, nullptr, kf, nullptr, nullptr, 2048};
    ZArg zv = {hh, hl, wsph(2), wspl(2), nullptr, nullptr, vf, nullptr, nullptr, 2048};
    gemm_hl<<<dim3(256, 1, 3), blk, 0, stream>>>(zq, zk, zv, 1024);
  }
  rope_split_kern<<<(B_ * S_ * NH_ * 32) / 256, blk, 0, stream>>>(qf, kf, kh, kl, posids, flags);
  vtrans_kern<<<dim3(16, 32), blk, 0, stream>>>(vf, vth, vtl, 1024);
  attn_hl<true><<<dim3(16, 32), blk, 0, stream>>>(
      qf, kh, kl, vth, vtl, oh, ol, nullptr, flags, 1024, 1024, 0.125f);
  {
    ZArg zo = {oh, ol, wsph(3), wspl(3), nullptr, x_in, x1, nullptr, nullptr, 2048};
    gemm_hl<<<dim3(256, 1, 1), blk, 0, stream>>>(zo, zo, zo, 1024);
  }

  // ---- cross-attention block ----
  rmsnorm_hl_kern<<<T_, blk, 0, stream>>>(x1, cnorm, h2h, h2l);
  {
    ZArg zcq = {h2h, h2l, wsph(4), wspl(4), cqb, nullptr, cqf, nullptr, nullptr, 2048};
    ZArg zck = {ench, encl, wsph(5), wspl(5), ckb, nullptr, nullptr, ckh, ckl, 1024};
    ZArg zcv = {ench, encl, wsph(6), wspl(6), cvb, nullptr, cvf, nullptr, nullptr, 1024};
    gemm_hl<<<dim3(256, 1, 3), blk, 0, stream>>>(zcq, zck, zcv, 1024);
  }
  vtrans_kern<<<dim3(8, 32), blk, 0, stream>>>(cvf, cvth, cvtl, 512);
  attn_hl<false><<<dim3(16, 32), blk, 0, stream>>>(
      cqf, ckh, ckl, cvth, cvtl, coh, col, emask, flags, 1024, 512, 0.125f);
  {
    ZArg zco = {coh, col, wsph(7), wspl(7), cob, x1, x2, nullptr, nullptr, 2048};
    gemm_hl<<<dim3(256, 1, 1), blk, 0, stream>>>(zco, zco, zco, 1024);
  }

  // ---- MoE block (weight cvt after last wsp use; stream is serial) ----
  cvt_all<<<49152, blk, 0, stream>>>(w1, w3, w2, w1b, w3b, w2b);
  rmsnorm_kern<<<T_, blk, 0, stream>>>(x2, pln, h3b);
  hipMemsetAsync(meta, 0, 64, stream);   // counts + cursor
  router_kern<<<T_, dim3(64), 0, stream>>>(x2, pln, gatew, topi, topw, counts);
  finalize_kern<<<1, blk, 0, stream>>>(counts, poff, tm_e, tm_slot, ntl, perm);
  scatter_kern<<<(T_ + 255) / 256, blk, 0, stream>>>(topi, topw, poff, cursor, perm, pwgt);
  moe_gemm1<<<768, dim3(512), 0, stream>>>(
      h3b, w1b, w3b, ffh, tm_e, tm_slot, ntl, perm);
  hipMemcpyAsync(out, x2, (size_t)T_ * H_ * 4, hipMemcpyDeviceToDevice, stream);
  moe_gemm2<<<768, blk, 0, stream>>>(
      ffh, w2b, out, tm_e, tm_slot, ntl, perm, pwgt);
}

// Round 11
// 537.953 us; speedup vs baseline: 1.1450x; 1.1450x over previous
//
#include <hip/hip_runtime.h>

// ---------------- problem constants ----------------
#define B_    2
#define S_    1024
#define H_    1024
#define NH_   16
#define HD_   64
#define SE_   512
#define E_    1024
#define NEXP_ 8
#define FF_   2048
#define T_    (B_*S_)    // 2048 tokens
#define TE_   (B_*SE_)   // 1024 encoder tokens
#define PERM_MAX 6400    // 256-padded slots: <= 4096 + 8*255 = 6136
#define MAXRT 24         // 256-row tiles

typedef short v8s __attribute__((ext_vector_type(8)));
typedef short v4s __attribute__((ext_vector_type(4)));
typedef float v4f __attribute__((ext_vector_type(4)));
typedef _Float16 v8h __attribute__((ext_vector_type(8)));
typedef _Float16 v4h __attribute__((ext_vector_type(4)));

__device__ __forceinline__ unsigned short f2b(float f) {
  unsigned int u = __float_as_uint(f);
  u = (u + 0x7FFFu + ((u >> 16) & 1u)) >> 16;   // RNE f32 -> bf16 bits
  return (unsigned short)u;
}

// async global->LDS, 16 bytes/lane; lds base wave-uniform, global per-lane
__device__ __forceinline__ void g2l16(const void* g, void* l) {
  __builtin_amdgcn_global_load_lds(
      (const __attribute__((address_space(1))) unsigned int*)g,
      (__attribute__((address_space(3))) unsigned int*)l, 16, 0, 0);
}

// ---------------- int64-vs-int32 ABI detect + meta zero ----------------
__global__ void detect_kern(const int* __restrict__ pos, const int* __restrict__ msk,
                            int* __restrict__ flags, int* __restrict__ counts) {
  if (threadIdx.x < 16) counts[threadIdx.x] = 0;   // counts + cursor region
  if (threadIdx.x == 0) {
    flags[0] = (pos[1] == 1) ? 0 : 1;
    flags[1] = (msk[1] == 1) ? 0 : 1;
  }
}

// ---------------- fused f32 -> fp16 hi/lo split (9 segments) ----------------
// segs 0-7: 1M f32 each (512 blocks); seg 8: enc 1M f32 (512 blocks) -> 4608
struct SplitArgs {
  const float* src[9];
  _Float16* dh[9];
  _Float16* dl[9];
};
__global__ __launch_bounds__(256)
void split_all(SplitArgs sa) {
  int b = blockIdx.x;
  int seg, i;
  if (b < 4096) { seg = b >> 9; i = (b & 511) * 256 + threadIdx.x; }
  else          { seg = 8;      i = (b - 4096) * 256 + threadIdx.x; }
  const float* x = sa.src[seg];
  v4f a = *(const v4f*)&x[i * 8];
  v4f c = *(const v4f*)&x[i * 8 + 4];
  v8h hv, lv;
  #pragma unroll
  for (int j = 0; j < 8; ++j) {
    float v = j < 4 ? a[j] : c[j - 4];
    _Float16 hh = (_Float16)v;
    hv[j] = hh; lv[j] = (_Float16)(v - (float)hh);
  }
  *(v8h*)&sa.dh[seg][i * 8] = hv;
  *(v8h*)&sa.dl[seg][i * 8] = lv;
}

// ---------------- fused f32 -> bf16 convert (MoE weights, 3 segments) -------
__global__ __launch_bounds__(256)
void cvt_all(const float* __restrict__ s0, const float* __restrict__ s1,
             const float* __restrict__ s2,
             unsigned short* __restrict__ d0, unsigned short* __restrict__ d1,
             unsigned short* __restrict__ d2) {
  int b = blockIdx.x;
  int seg = b >> 14;                 // 16384 blocks per segment
  int i = (b & 16383) * 256 + threadIdx.x;
  const float* x = seg == 0 ? s0 : (seg == 1 ? s1 : s2);
  unsigned short* y = seg == 0 ? d0 : (seg == 1 ? d1 : d2);
  v4f v = *(const v4f*)&x[i * 4];
  v4s o;
  #pragma unroll
  for (int j = 0; j < 4; ++j) o[j] = (short)f2b(v[j]);
  *(v4s*)&y[i * 4] = o;
}

// ---------------- RMSNorm f32 -> fp16 hi/lo ----------------
__global__ __launch_bounds__(256)
void rmsnorm_hl_kern(const float* __restrict__ x, const float* __restrict__ w,
                     _Float16* __restrict__ yh, _Float16* __restrict__ yl) {
  int row = blockIdx.x, tid = threadIdx.x;
  const float* xr = x + (long)row * 1024;
  v4f v = *(const v4f*)&xr[tid * 4];
  float ss = v[0]*v[0] + v[1]*v[1] + v[2]*v[2] + v[3]*v[3];
  #pragma unroll
  for (int off = 32; off; off >>= 1) ss += __shfl_xor(ss, off);
  __shared__ float sw[4];
  if ((tid & 63) == 0) sw[tid >> 6] = ss;
  __syncthreads();
  float tot = sw[0] + sw[1] + sw[2] + sw[3];
  float rs = rsqrtf(tot * (1.0f / 1024.0f) + 1e-6f);
  const float* wr = w + tid * 4;
  v4h oh, ol;
  #pragma unroll
  for (int j = 0; j < 4; ++j) {
    float f = v[j] * rs * wr[j];
    _Float16 hh = (_Float16)f;
    oh[j] = hh; ol[j] = (_Float16)(f - (float)hh);
  }
  *(v4h*)&yh[(long)row * 1024 + tid * 4] = oh;
  *(v4h*)&yl[(long)row * 1024 + tid * 4] = ol;
}

// ---------------- RMSNorm f32 -> bf16 (MoE h3) ----------------
__global__ __launch_bounds__(256)
void rmsnorm_kern(const float* __restrict__ x, const float* __restrict__ w,
                  unsigned short* __restrict__ y) {
  int row = blockIdx.x, tid = threadIdx.x;
  const float* xr = x + (long)row * 1024;
  v4f v = *(const v4f*)&xr[tid * 4];
  float ss = v[0]*v[0] + v[1]*v[1] + v[2]*v[2] + v[3]*v[3];
  #pragma unroll
  for (int off = 32; off; off >>= 1) ss += __shfl_xor(ss, off);
  __shared__ float sw[4];
  if ((tid & 63) == 0) sw[tid >> 6] = ss;
  __syncthreads();
  float tot = sw[0] + sw[1] + sw[2] + sw[3];
  float rs = rsqrtf(tot * (1.0f / 1024.0f) + 1e-6f);
  const float* wr = w + tid * 4;
  v4s o;
  #pragma unroll
  for (int j = 0; j < 4; ++j) o[j] = (short)f2b(v[j] * rs * wr[j]);
  *(v4s*)&y[(long)row * 1024 + tid * 4] = o;
}

// ---------------- RoPE: q f32 in-place; k rotated -> fp16 hi/lo ----------
__global__ __launch_bounds__(256)
void rope_split_kern(float* __restrict__ q, const float* __restrict__ k,
                     _Float16* __restrict__ kh, _Float16* __restrict__ kl,
                     const int* __restrict__ pos, const int* __restrict__ flags) {
  int g = blockIdx.x * 256 + threadIdx.x;
  int d = g & 31;
  int h = (g >> 5) & 15;
  int s = (g >> 9) & (S_ - 1);
  int b = g >> 19;
  long base = (((long)(b * S_ + s)) * NH_ + h) * HD_;
  int pidx = b * S_ + s;
  int pv = pos[flags[0] ? (pidx << 1) : pidx];
  float p = (float)pv;
  float inv = powf(10000.0f, -(float)d * (1.0f / 32.0f));
  float f = p * inv;
  float sn = sinf(f), cs = cosf(f);
  float q1 = q[base + d], q2 = q[base + d + 32];
  q[base + d]      = q1 * cs - q2 * sn;
  q[base + d + 32] = q2 * cs + q1 * sn;
  float k1 = k[base + d], k2 = k[base + d + 32];
  float kr1 = k1 * cs - k2 * sn;
  float kr2 = k2 * cs + k1 * sn;
  _Float16 hh = (_Float16)kr1;
  kh[base + d] = hh; kl[base + d] = (_Float16)(kr1 - (float)hh);
  hh = (_Float16)kr2;
  kh[base + d + 32] = hh; kl[base + d + 32] = (_Float16)(kr2 - (float)hh);
}

// ---------------- V transpose + split: [B,Sk,NH,64]f32 -> [B,NH,64,Sk]f16 x2
__global__ __launch_bounds__(256)
void vtrans_kern(const float* __restrict__ vf, _Float16* __restrict__ vth,
                 _Float16* __restrict__ vtl, int Sk) {
  int kb = blockIdx.x, bh = blockIdx.y;
  int b = bh >> 4, h = bh & 15;
  int t = threadIdx.x;
  __shared__ float tile[64][65];
  int key = t >> 2, dsub = (t & 3) * 16;
  const float* src = vf + (((long)(b * Sk + kb * 64 + key)) * NH_ + h) * HD_ + dsub;
  #pragma unroll
  for (int j = 0; j < 16; j += 4) *(v4f*)&tile[key][dsub + j] = *(const v4f*)&src[j];
  __syncthreads();
  int d = t >> 2, ksub = (t & 3) * 16;
  v8h hv0, lv0, hv1, lv1;
  #pragma unroll
  for (int j = 0; j < 16; ++j) {
    float v = tile[ksub + j][d];
    _Float16 hh = (_Float16)v;
    if (j < 8) { hv0[j] = hh; lv0[j] = (_Float16)(v - (float)hh); }
    else       { hv1[j - 8] = hh; lv1[j - 8] = (_Float16)(v - (float)hh); }
  }
  long ob = (((long)(b * NH_ + h)) * HD_ + d) * Sk + kb * 64 + ksub;
  *(v8h*)&vth[ob] = hv0; *(v8h*)&vth[ob + 8] = hv1;
  *(v8h*)&vtl[ob] = lv0; *(v8h*)&vtl[ob + 8] = lv1;
}

// ---------------- split-fp16 3-pass GEMM, 128x64 tile, dbuf, XCD-swizzled ---
struct ZArg {
  const _Float16 *Ah, *Al, *Bh, *Bl;
  const float *bias, *resid;
  float *Cf;
  float *Cf2;           // optional second f32 destination (dual write)
  _Float16 *Ch, *Cl;
  int M;
};

__global__ __launch_bounds__(256)
void gemm_hl(ZArg z0, ZArg z1, ZArg z2, int K) {
  ZArg za = blockIdx.z == 0 ? z0 : (blockIdx.z == 1 ? z1 : z2);
  int flat = blockIdx.x;                       // 256 per z
  int wg = (flat & 7) * 32 + (flat >> 3);      // XCD swizzle (256 = 8*32)
  int row0 = (wg >> 4) * 128;
  int col0 = (wg & 15) * 64;
  if (row0 >= za.M) return;
  int tid = threadIdx.x, lane = tid & 63, w = tid >> 6;
  int lr = lane & 15, lg = lane >> 4;
  int wr = w >> 1, wc = w & 1;
  int rsw = (lr >> 1) & 3;           // read-side swizzle

  __shared__ _Float16 Ah_s[2][128 * 32], Al_s[2][128 * 32];   // 32 KB
  __shared__ _Float16 Bh_s[2][64 * 32], Bl_s[2][64 * 32];     // 16 KB

  int av0 = w * 64 + lane, av1 = (w + 4) * 64 + lane;
  int ar0 = av0 >> 2, as0 = (av0 & 3) ^ ((ar0 >> 1) & 3);
  int ar1 = av1 >> 2, as1 = (av1 & 3) ^ ((ar1 >> 1) & 3);
  int bv = w * 64 + lane;
  int br = bv >> 2, bs = (bv & 3) ^ ((br >> 1) & 3);
  const _Float16* ga0h = za.Ah + (long)(row0 + ar0) * K + as0 * 8;
  const _Float16* ga0l = za.Al + (long)(row0 + ar0) * K + as0 * 8;
  const _Float16* ga1h = za.Ah + (long)(row0 + ar1) * K + as1 * 8;
  const _Float16* ga1l = za.Al + (long)(row0 + ar1) * K + as1 * 8;
  const _Float16* gbh  = za.Bh + (long)(col0 + br) * K + bs * 8;
  const _Float16* gbl  = za.Bl + (long)(col0 + br) * K + bs * 8;

  auto stage = [&](int buf, int k0) {
    g2l16(ga0h + k0, (char*)Ah_s[buf] + w * 1024);
    g2l16(ga1h + k0, (char*)Ah_s[buf] + (w + 4) * 1024);
    g2l16(ga0l + k0, (char*)Al_s[buf] + w * 1024);
    g2l16(ga1l + k0, (char*)Al_s[buf] + (w + 4) * 1024);
    g2l16(gbh + k0, (char*)Bh_s[buf] + w * 1024);
    g2l16(gbl + k0, (char*)Bl_s[buf] + w * 1024);
  };

  v4f acc[4][2] = {};
  stage(0, 0);
  int cur = 0;

  for (int k0 = 0; k0 < K; k0 += 32) {
    __syncthreads();                       // drains stage(cur) issued last iter
    if (k0 + 32 < K) stage(cur ^ 1, k0 + 32);   // fly under this iter's MFMA

    v8h ah[4], al[4], bh[2], bl[2];
    #pragma unroll
    for (int m = 0; m < 4; ++m) {
      int off = (wr * 64 + m * 16 + lr) * 64 + ((lg ^ rsw) << 4);
      ah[m] = *(const v8h*)((char*)Ah_s[cur] + off);
      al[m] = *(const v8h*)((char*)Al_s[cur] + off);
    }
    #pragma unroll
    for (int n = 0; n < 2; ++n) {
      int off = (wc * 32 + n * 16 + lr) * 64 + ((lg ^ rsw) << 4);
      bh[n] = *(const v8h*)((char*)Bh_s[cur] + off);
      bl[n] = *(const v8h*)((char*)Bl_s[cur] + off);
    }
    #pragma unroll
    for (int m = 0; m < 4; ++m)
      #pragma unroll
      for (int n = 0; n < 2; ++n) {
        acc[m][n] = __builtin_amdgcn_mfma_f32_16x16x32_f16(ah[m], bh[n], acc[m][n], 0, 0, 0);
        acc[m][n] = __builtin_amdgcn_mfma_f32_16x16x32_f16(ah[m], bl[n], acc[m][n], 0, 0, 0);
        acc[m][n] = __builtin_amdgcn_mfma_f32_16x16x32_f16(al[m], bh[n], acc[m][n], 0, 0, 0);
      }
    cur ^= 1;
  }

  #pragma unroll
  for (int m = 0; m < 4; ++m) {
    int rbase = row0 + wr * 64 + m * 16 + lg * 4;
    #pragma unroll
    for (int n = 0; n < 2; ++n) {
      int gcol = col0 + wc * 32 + n * 16 + lr;
      float bb = za.bias ? za.bias[gcol] : 0.0f;
      #pragma unroll
      for (int rr = 0; rr < 4; ++rr) {
        long idx = (long)(rbase + rr) * 1024 + gcol;
        float v = acc[m][n][rr] + bb;
        if (za.Cf) {
          float r = za.resid ? (za.resid[idx] + v) : v;
          za.Cf[idx] = r;
          if (za.Cf2) za.Cf2[idx] = r;
        } else {
          _Float16 hh = (_Float16)v;
          za.Ch[idx] = hh;
          za.Cl[idx] = (_Float16)(v - (float)hh);
        }
      }
    }
  }
}

// ---------------- flash attention: pre-split K/V^T, gload_lds, XCD-swz ------
// 1D grid 512: each XCD owns 4 complete (b,h) groups -> K/V stay in its L2.
template<bool CAUSAL>
__global__ __launch_bounds__(256)
void attn_hl(const float* __restrict__ Q,
             const _Float16* __restrict__ Khg, const _Float16* __restrict__ Klg,
             const _Float16* __restrict__ Vhg, const _Float16* __restrict__ Vlg,
             _Float16* __restrict__ Oh, _Float16* __restrict__ Ol,
             const int* __restrict__ mask, const int* __restrict__ flags,
             int Sq, int Sk, float qscale) {
  int flat = blockIdx.x;                       // 512 = 8 * 64
  int wgA = (flat & 7) * 64 + (flat >> 3);     // XCD swizzle
  int qt = wgA & 15, bh = wgA >> 4;
  int b = bh >> 4, h = bh & 15;
  int tid = threadIdx.x, lane = tid & 63, w = tid >> 6;
  int lr = lane & 15, lg = lane >> 4;
  int q0 = qt * 64;
  int mf = (!CAUSAL && mask) ? flags[1] : 0;
  int swz = lr & 7;

  __shared__ _Float16 Kh_s[64 * 64], Kl_s[64 * 64];
  __shared__ _Float16 Vh_s[64 * 64], Vl_s[64 * 64];
  __shared__ _Float16 Psh[4][16][72], Psl[4][16][72];

  v8h qh[2], ql[2];
  {
    long qbase = ((long)(b * Sq + q0 + w * 16 + lr) * NH_ + h) * HD_;
    #pragma unroll
    for (int kk = 0; kk < 2; ++kk) {
      v4f f0 = *(const v4f*)&Q[qbase + kk * 32 + lg * 8];
      v4f f1 = *(const v4f*)&Q[qbase + kk * 32 + lg * 8 + 4];
      #pragma unroll
      for (int j = 0; j < 8; ++j) {
        float f = (j < 4 ? f0[j] : f1[j - 4]) * qscale;
        _Float16 hh = (_Float16)f;
        qh[kk][j] = hh;
        ql[kk][j] = (_Float16)(f - (float)hh);
      }
    }
  }
  v4f of[4] = {};
  float m4[4], l4[4];
  #pragma unroll
  for (int i = 0; i < 4; ++i) { m4[i] = -3e38f; l4[i] = 0.0f; }

  int nkt = CAUSAL ? (qt + 1) : (Sk >> 6);
  for (int kt = 0; kt < nkt; ++kt) {
    __syncthreads();
    #pragma unroll
    for (int i = 0; i < 2; ++i) {
      int c = w + i * 4;
      int v = c * 64 + lane;
      int row = v >> 3, c8 = v & 7;
      int sc = (c8 ^ (row & 7)) << 3;
      long kb = ((long)(b * Sk + kt * 64 + row) * NH_ + h) * HD_ + sc;
      g2l16(Khg + kb, (char*)Kh_s + c * 1024);
      g2l16(Klg + kb, (char*)Kl_s + c * 1024);
      long vb = ((long)(b * NH_ + h) * HD_ + row) * Sk + kt * 64 + sc;
      g2l16(Vhg + vb, (char*)Vh_s + c * 1024);
      g2l16(Vlg + vb, (char*)Vl_s + c * 1024);
    }
    __syncthreads();

    v4f sf[4] = {};
    #pragma unroll
    for (int kk = 0; kk < 2; ++kk)
      #pragma unroll
      for (int n = 0; n < 4; ++n) {
        int off = (n * 16 + lr) * 128 + ((((kk << 2) | lg) ^ swz) << 4);
        v8h kbh = *(const v8h*)((char*)Kh_s + off);
        v8h kbl = *(const v8h*)((char*)Kl_s + off);
        sf[n] = __builtin_amdgcn_mfma_f32_16x16x32_f16(qh[kk], kbh, sf[n], 0, 0, 0);
        sf[n] = __builtin_amdgcn_mfma_f32_16x16x32_f16(qh[kk], kbl, sf[n], 0, 0, 0);
        sf[n] = __builtin_amdgcn_mfma_f32_16x16x32_f16(ql[kk], kbh, sf[n], 0, 0, 0);
      }

    if constexpr (CAUSAL) {
      if (kt == qt) {
        #pragma unroll
        for (int n = 0; n < 4; ++n) {
          int kcol = kt * 64 + n * 16 + lr;
          #pragma unroll
          for (int rr = 0; rr < 4; ++rr) {
            int qr = q0 + w * 16 + lg * 4 + rr;
            if (kcol > qr) sf[n][rr] = -1e9f;
          }
        }
      }
    } else {
      if (mask) {
        #pragma unroll
        for (int n = 0; n < 4; ++n) {
          int kcol = kt * 64 + n * 16 + lr;
          int mi = b * Sk + kcol;
          if (mask[mf ? (mi << 1) : mi] == 0) {
            #pragma unroll
            for (int rr = 0; rr < 4; ++rr) sf[n][rr] = -1e9f;
          }
        }
      }
    }

    float al[4];
    #pragma unroll
    for (int rr = 0; rr < 4; ++rr) {
      float mx = fmaxf(fmaxf(sf[0][rr], sf[1][rr]), fmaxf(sf[2][rr], sf[3][rr]));
      #pragma unroll
      for (int off = 8; off; off >>= 1) mx = fmaxf(mx, __shfl_xor(mx, off));
      float mn = fmaxf(m4[rr], mx);
      al[rr] = __expf(m4[rr] - mn);
      m4[rr] = mn;
      float rs = 0.0f;
      #pragma unroll
      for (int n = 0; n < 4; ++n) {
        float pv = __expf(sf[n][rr] - mn);
        sf[n][rr] = pv;
        rs += pv;
      }
      #pragma unroll
      for (int off = 8; off; off >>= 1) rs += __shfl_xor(rs, off);
      l4[rr] = l4[rr] * al[rr] + rs;
    }

    #pragma unroll
    for (int n = 0; n < 4; ++n)
      #pragma unroll
      for (int rr = 0; rr < 4; ++rr) {
        of[n][rr] *= al[rr];
        float pv = sf[n][rr];
        _Float16 ph = (_Float16)pv;
        Psh[w][lg * 4 + rr][n * 16 + lr] = ph;
        Psl[w][lg * 4 + rr][n * 16 + lr] = (_Float16)(pv - (float)ph);
      }
    __syncthreads();

    #pragma unroll
    for (int kc = 0; kc < 2; ++kc) {
      v8h pah = *(const v8h*)&Psh[w][lr][kc * 32 + lg * 8];
      v8h pal = *(const v8h*)&Psl[w][lr][kc * 32 + lg * 8];
      #pragma unroll
      for (int n = 0; n < 4; ++n) {
        int off = (n * 16 + lr) * 128 + ((((kc << 2) | lg) ^ swz) << 4);
        v8h vbh = *(const v8h*)((char*)Vh_s + off);
        v8h vbl = *(const v8h*)((char*)Vl_s + off);
        of[n] = __builtin_amdgcn_mfma_f32_16x16x32_f16(pah, vbh, of[n], 0, 0, 0);
        of[n] = __builtin_amdgcn_mfma_f32_16x16x32_f16(pah, vbl, of[n], 0, 0, 0);
        of[n] = __builtin_amdgcn_mfma_f32_16x16x32_f16(pal, vbh, of[n], 0, 0, 0);
      }
    }
  }

  #pragma unroll
  for (int rr = 0; rr < 4; ++rr) {
    int qr = q0 + w * 16 + lg * 4 + rr;
    float inv = 1.0f / l4[rr];
    long ob = (long)(b * Sq + qr) * 1024 + h * 64;
    #pragma unroll
    for (int n = 0; n < 4; ++n) {
      float v = of[n][rr] * inv;
      _Float16 hh = (_Float16)v;
      Oh[ob + n * 16 + lr] = hh;
      Ol[ob + n * 16 + lr] = (_Float16)(v - (float)hh);
    }
  }
}

// ---------------- MoE GEMM1: 256x64 tile, 8 waves, dual-B, dbuf, XCD-swz ----
__global__ __launch_bounds__(512)
void moe_gemm1(const unsigned short* __restrict__ A,
               const unsigned short* __restrict__ B1,
               const unsigned short* __restrict__ B2,
               unsigned short* __restrict__ Cb,
               const int* __restrict__ tm_e, const int* __restrict__ tm_slot,
               const int* __restrict__ ntl, const int* __restrict__ perm) {
  int flat = blockIdx.x;                        // 768 = 8*96
  int wg = (flat & 7) * 96 + (flat >> 3);       // XCD swizzle
  int tile = wg >> 5;
  if (tile >= ntl[0]) return;
  int col0 = (wg & 31) * 64;
  int e = tm_e[tile];
  int row0 = tm_slot[tile];
  const unsigned short* Bp1 = B1 + (long)e * (FF_ * H_);
  const unsigned short* Bp2 = B2 + (long)e * (FF_ * H_);
  int tid = threadIdx.x, lane = tid & 63, w = tid >> 6;   // 8 waves
  int lr = lane & 15, lg = lane >> 4;
  int wr = w >> 1, wc = w & 1;
  int rsw = (lr >> 1) & 3;

  __shared__ unsigned short As[2][256 * 32];    // 32 KB
  __shared__ unsigned short Bs1[2][64 * 32];    // 8 KB
  __shared__ unsigned short Bs2[2][64 * 32];    // 8 KB

  const unsigned short* ga[2];
  #pragma unroll
  for (int i = 0; i < 2; ++i) {
    int c = i * 512 + tid;
    int r = c >> 2, sub = (c & 3) ^ ((r >> 1) & 3);
    int tok = perm[row0 + r];
    ga[i] = A + (long)(tok < 0 ? 0 : tok) * H_ + sub * 8;
  }
  int bc = tid & 255;
  int rb = bc >> 2, sb = (bc & 3) ^ ((rb >> 1) & 3);
  const unsigned short* gB = (tid < 256 ? Bp1 : Bp2) + (long)(col0 + rb) * H_ + sb * 8;
  size_t lBoff = (size_t)((w & 3) * 64) * 8;

  auto stage = [&](int buf, int k0) {
    #pragma unroll
    for (int i = 0; i < 2; ++i)
      g2l16(ga[i] + k0, As[buf] + (size_t)(i * 512 + w * 64) * 8);
    g2l16(gB + k0, (tid < 256 ? Bs1[buf] : Bs2[buf]) + lBoff);
  };

  v4f acc[4][2] = {};
  v4f acc2[4][2] = {};
  stage(0, 0);
  int cur = 0;

  for (int k0 = 0; k0 < H_; k0 += 32) {
    __syncthreads();
    if (k0 + 32 < H_) stage(cur ^ 1, k0 + 32);

    v8s a[4], b1[2], b2[2];
    #pragma unroll
    for (int m = 0; m < 4; ++m)
      a[m] = *(const v8s*)&As[cur][(wr * 64 + m * 16 + lr) * 32 + (lg ^ rsw) * 8];
    #pragma unroll
    for (int n = 0; n < 2; ++n) {
      b1[n] = *(const v8s*)&Bs1[cur][(wc * 32 + n * 16 + lr) * 32 + (lg ^ rsw) * 8];
      b2[n] = *(const v8s*)&Bs2[cur][(wc * 32 + n * 16 + lr) * 32 + (lg ^ rsw) * 8];
    }
    #pragma unroll
    for (int m = 0; m < 4; ++m)
      #pragma unroll
      for (int n = 0; n < 2; ++n) {
        acc[m][n]  = __builtin_amdgcn_mfma_f32_16x16x32_bf16(a[m], b1[n], acc[m][n], 0, 0, 0);
        acc2[m][n] = __builtin_amdgcn_mfma_f32_16x16x32_bf16(a[m], b2[n], acc2[m][n], 0, 0, 0);
      }
    cur ^= 1;
  }

  #pragma unroll
  for (int m = 0; m < 4; ++m) {
    int grow = row0 + wr * 64 + m * 16 + lg * 4;
    #pragma unroll
    for (int n = 0; n < 2; ++n) {
      int gcol = col0 + wc * 32 + n * 16 + lr;
      #pragma unroll
      for (int rr = 0; rr < 4; ++rr) {
        float v = acc[m][n][rr];
        float g = v / (1.0f + __expf(-v));
        Cb[(long)(grow + rr) * FF_ + gcol] = f2b(g * acc2[m][n][rr]);
      }
    }
  }
}

// ---------------- MoE GEMM2: 128x64 tile, 4 waves (32-row strips), scatter --
__global__ __launch_bounds__(256)
void moe_gemm2(const unsigned short* __restrict__ A,
               const unsigned short* __restrict__ B,
               float* __restrict__ Cf,
               const int* __restrict__ tm_e, const int* __restrict__ tm_slot,
               const int* __restrict__ ntl,
               const int* __restrict__ perm, const float* __restrict__ pwgt) {
  int flat = blockIdx.x;                        // 768 = 8*96
  int wg = (flat & 7) * 96 + (flat >> 3);       // XCD swizzle
  int t2 = wg >> 4;                             // 0..47 (128-row sub-tiles)
  int tile = t2 >> 1;
  if (tile >= ntl[0]) return;
  int row0 = tm_slot[tile] + (t2 & 1) * 128;
  int col0 = (wg & 15) * 64;
  int e = tm_e[tile];
  const unsigned short* Bp = B + (long)e * (H_ * FF_);
  int tid = threadIdx.x, lane = tid & 63, w = tid >> 6;   // 4 waves
  int lr = lane & 15, lg = lane >> 4;
  int rsw = (lr >> 1) & 3;

  __shared__ unsigned short As[2][128 * 32];    // 16 KB
  __shared__ unsigned short Bs[2][64 * 32];     // 8 KB

  const unsigned short* ga[2];
  #pragma unroll
  for (int i = 0; i < 2; ++i) {
    int c = i * 256 + tid;
    int r = c >> 2, sub = (c & 3) ^ ((r >> 1) & 3);
    ga[i] = A + (long)(row0 + r) * FF_ + sub * 8;
  }
  int rb = tid >> 2, sb = (tid & 3) ^ ((rb >> 1) & 3);
  const unsigned short* gb = Bp + (long)(col0 + rb) * FF_ + sb * 8;

  auto stage = [&](int buf, int k0) {
    #pragma unroll
    for (int i = 0; i < 2; ++i)
      g2l16(ga[i] + k0, As[buf] + (size_t)(i * 256 + w * 64) * 8);
    g2l16(gb + k0, Bs[buf] + (size_t)(w * 64) * 8);
  };

  // wave w owns rows [w*32, w*32+32), all 64 cols: acc[2][4]
  v4f acc[2][4] = {};
  stage(0, 0);
  int cur = 0;

  for (int k0 = 0; k0 < FF_; k0 += 32) {
    __syncthreads();
    if (k0 + 32 < FF_) stage(cur ^ 1, k0 + 32);

    v8s a[2], b[4];
    #pragma unroll
    for (int m = 0; m < 2; ++m)
      a[m] = *(const v8s*)&As[cur][(w * 32 + m * 16 + lr) * 32 + (lg ^ rsw) * 8];
    #pragma unroll
    for (int n = 0; n < 4; ++n)
      b[n] = *(const v8s*)&Bs[cur][(n * 16 + lr) * 32 + (lg ^ rsw) * 8];
    #pragma unroll
    for (int m = 0; m < 2; ++m)
      #pragma unroll
      for (int n = 0; n < 4; ++n)
        acc[m][n] = __builtin_amdgcn_mfma_f32_16x16x32_bf16(a[m], b[n], acc[m][n], 0, 0, 0);
    cur ^= 1;
  }

  #pragma unroll
  for (int m = 0; m < 2; ++m) {
    int grow = row0 + w * 32 + m * 16 + lg * 4;
    #pragma unroll
    for (int rr = 0; rr < 4; ++rr) {
      int tok = perm[grow + rr];
      if (tok < 0) continue;
      float pw = pwgt[grow + rr];
      #pragma unroll
      for (int n = 0; n < 4; ++n) {
        int gcol = col0 + n * 16 + lr;
        atomicAdd(&Cf[(long)tok * H_ + gcol], acc[m][n][rr] * pw);
      }
    }
  }
}

// ---------------- MoE router: f32 rms + logits + top-2 ----------------
__global__ __launch_bounds__(64)
void router_kern(const float* __restrict__ x, const float* __restrict__ w,
                 const float* __restrict__ gw,
                 int* __restrict__ topi, float* __restrict__ topw,
                 int* __restrict__ counts) {
  int t = blockIdx.x, lane = threadIdx.x;
  const float* xr = x + (long)t * 1024;
  float vals[16];
  float ss = 0.0f;
  #pragma unroll
  for (int i = 0; i < 16; ++i) { float v = xr[lane + i * 64]; vals[i] = v; ss += v * v; }
  #pragma unroll
  for (int off = 32; off; off >>= 1) ss += __shfl_xor(ss, off);
  float rs = rsqrtf(ss * (1.0f / 1024.0f) + 1e-6f);
  #pragma unroll
  for (int i = 0; i < 16; ++i) vals[i] *= rs * w[lane + i * 64];
  float lgts[8];
  #pragma unroll
  for (int e = 0; e < 8; ++e) {
    const float* g = gw + e * 1024;
    float s = 0.0f;
    #pragma unroll
    for (int i = 0; i < 16; ++i) s += vals[i] * g[lane + i * 64];
    #pragma unroll
    for (int off = 32; off; off >>= 1) s += __shfl_xor(s, off);
    lgts[e] = s;
  }
  int i1 = 0; float l1 = lgts[0];
  #pragma unroll
  for (int e = 1; e < 8; ++e) if (lgts[e] > l1) { l1 = lgts[e]; i1 = e; }
  int i2 = -1; float l2 = -3e38f;
  #pragma unroll
  for (int e = 0; e < 8; ++e) if (e != i1 && lgts[e] > l2) { l2 = lgts[e]; i2 = e; }
  float w1 = 1.0f / (1.0f + __expf(l2 - l1));
  if (lane == 0) {
    topi[t * 2] = i1; topi[t * 2 + 1] = i2;
    topw[t * 2] = w1; topw[t * 2 + 1] = 1.0f - w1;
    atomicAdd(&counts[i1], 1);
    atomicAdd(&counts[i2], 1);
  }
}

// ---------------- merged finalize + scatter (single block, LDS cursors) -----
__global__ __launch_bounds__(256)
void route_pack_kern(const int* __restrict__ counts,
                     const int* __restrict__ topi, const float* __restrict__ topw,
                     int* __restrict__ poff,
                     int* __restrict__ tm_e, int* __restrict__ tm_slot,
                     int* __restrict__ ntl,
                     int* __restrict__ perm, float* __restrict__ pwgt) {
  __shared__ int s_poff[8];
  __shared__ int s_cur[8];
  __shared__ int stot;
  if (threadIdx.x < 8) s_cur[threadIdx.x] = 0;
  if (threadIdx.x == 0) {
    int off = 0, nt = 0;
    for (int e = 0; e < 8; ++e) {
      s_poff[e] = off; poff[e] = off;
      int c = counts[e];
      int ntE = (c + 255) >> 8;
      for (int i = 0; i < ntE; ++i) { tm_e[nt] = e; tm_slot[nt] = off + i * 256; ++nt; }
      off += ntE * 256;
    }
    ntl[0] = nt; ntl[1] = off;
    stot = off;
  }
  __syncthreads();
  for (int s = threadIdx.x; s < stot; s += 256) perm[s] = -1;
  __syncthreads();
  for (int t = threadIdx.x; t < T_; t += 256) {
    #pragma unroll
    for (int kk = 0; kk < 2; ++kk) {
      int e = topi[t * 2 + kk];
      int pos = atomicAdd(&s_cur[e], 1);
      int slot = s_poff[e] + pos;
      perm[slot] = t;
      pwgt[slot] = topw[t * 2 + kk];
    }
  }
}

// ---------------- host launcher ----------------
extern "C" void kernel_launch(void* const* d_in, const int* in_sizes, int n_in,
                              void* d_out, int out_size, void* d_ws, size_t ws_size,
                              hipStream_t stream) {
  (void)in_sizes; (void)n_in; (void)out_size; (void)ws_size;
  const float* x_in  = (const float*)d_in[0];
  const int*  posids = (const int*)d_in[1];
  const float* enc   = (const float*)d_in[2];
  const int*  emask  = (const int*)d_in[3];
  const float* inln  = (const float*)d_in[4];
  const float* wq    = (const float*)d_in[5];
  const float* wk    = (const float*)d_in[6];
  const float* wv    = (const float*)d_in[7];
  const float* wo    = (const float*)d_in[8];
  const float* cnorm = (const float*)d_in[9];
  const float* cqw   = (const float*)d_in[10];
  const float* cqb   = (const float*)d_in[11];
  const float* ckw   = (const float*)d_in[12];
  const float* ckb   = (const float*)d_in[13];
  const float* cvw   = (const float*)d_in[14];
  const float* cvb   = (const float*)d_in[15];
  const float* cow   = (const float*)d_in[16];
  const float* cob   = (const float*)d_in[17];
  const float* pln   = (const float*)d_in[18];
  const float* gatew = (const float*)d_in[19];
  const float* w1    = (const float*)d_in[20];
  const float* w2    = (const float*)d_in[21];
  const float* w3    = (const float*)d_in[22];
  float* out = (float*)d_out;

  char* p = (char*)d_ws;
  auto alloc = [&](size_t bytes) -> char* {
    char* r = p;
    p += (bytes + 255) & ~(size_t)255;
    return r;
  };
  const size_t MB = 1024 * 1024;
  char* A1 = alloc(4 * MB);   // hh -> oh -> ckh
  char* A2 = alloc(4 * MB);   // hl -> ol -> ckl
  char* Bq = alloc(8 * MB);   // qf -> cqf -> ffh
  char* Bk = alloc(8 * MB);   // kf -> cvth/cvtl -> ffh
  char* Bv = alloc(8 * MB);   // vf -> cvf -> ffh
  char* C1 = alloc(4 * MB);   // kh -> h2h -> ffh tail (dead by MoE)
  char* C2 = alloc(4 * MB);   // kl -> h2l
  char* D1 = alloc(4 * MB);   // vth -> coh
  char* D2 = alloc(4 * MB);   // vtl -> col
  float* x1 = (float*)alloc(8 * MB);
  float* x2 = (float*)alloc(8 * MB);
  unsigned short* h3b = (unsigned short*)alloc(4 * MB);
  _Float16* ench = (_Float16*)alloc(2 * MB);
  _Float16* encl = (_Float16*)alloc(2 * MB);
  int*   meta    = (int*)alloc(4 * (8 + 8 + 8 + 2 + 2 + MAXRT + MAXRT));
  int*   counts  = meta;
  int*   poff    = meta + 16;
  int*   ntl     = meta + 24;
  int*   flags   = meta + 26;
  int*   tm_e    = meta + 28;
  int*   tm_slot = meta + 28 + MAXRT;
  int*   topi    = (int*)alloc((size_t)T_ * 2 * 4);
  float* topw    = (float*)alloc((size_t)T_ * 2 * 4);
  int*   perm    = (int*)alloc((size_t)PERM_MAX * 4);
  float* pwgt    = (float*)alloc((size_t)PERM_MAX * 4);
  unsigned short* w1b = (unsigned short*)alloc((size_t)NEXP_ * FF_ * H_ * 2);  // 32 MB, also wsp
  unsigned short* w3b = (unsigned short*)alloc((size_t)NEXP_ * FF_ * H_ * 2);
  unsigned short* w2b = (unsigned short*)alloc((size_t)NEXP_ * H_ * FF_ * 2);

  // aliased views
  _Float16 *hh = (_Float16*)A1, *hl = (_Float16*)A2;
  _Float16 *oh = (_Float16*)A1, *ol = (_Float16*)A2;
  _Float16 *ckh = (_Float16*)A1, *ckl = (_Float16*)A2;
  float* qf = (float*)Bq;  float* cqf = (float*)Bq;
  float* kf = (float*)Bk;
  _Float16 *cvth = (_Float16*)Bk, *cvtl = (_Float16*)(Bk + 4 * MB);
  float* vf = (float*)Bv;  float* cvf = (float*)Bv;
  _Float16 *kh = (_Float16*)C1, *kl = (_Float16*)C2;
  _Float16 *h2h = (_Float16*)C1, *h2l = (_Float16*)C2;
  _Float16 *vth = (_Float16*)D1, *vtl = (_Float16*)D2;
  _Float16 *coh = (_Float16*)D1, *col = (_Float16*)D2;
  unsigned short* ffh = (unsigned short*)Bq;   // spans Bq..Bv + C1 (28MB > 25.1)
  _Float16* wsp = (_Float16*)w1b;              // split weights until MoE cvt
  auto wsph = [&](int i) { return wsp + (size_t)i * 2097152; };
  auto wspl = [&](int i) { return wsp + (size_t)i * 2097152 + 1048576; };

  dim3 blk(256);

  detect_kern<<<1, 64, 0, stream>>>(posids, emask, flags, counts);

  // fused pre-split of 8 attention weights + encoder states (4096+512 blocks)
  {
    SplitArgs sa;
    const float* wlist[8] = {wq, wk, wv, wo, cqw, ckw, cvw, cow};
    for (int i = 0; i < 8; ++i) { sa.src[i] = wlist[i]; sa.dh[i] = wsph(i); sa.dl[i] = wspl(i); }
    sa.src[8] = enc; sa.dh[8] = ench; sa.dl[8] = encl;
    split_all<<<4608, blk, 0, stream>>>(sa);
  }

  // ---- self-attention block ----
  rmsnorm_hl_kern<<<T_, blk, 0, stream>>>(x_in, inln, hh, hl);
  {
    ZArg zq = {hh, hl, wsph(0), wspl(0), nullptr, nullptr, qf, nullptr, nullptr, nullptr, 2048};
    ZArg zk = {hh, hl, wsph(1), wspl(1), nullptr, nullptr, kf, nullptr, nullptr, nullptr, 2048};
    ZArg zv = {hh, hl, wsph(2), wspl(2), nullptr, nullptr, vf, nullptr, nullptr, nullptr, 2048};
    gemm_hl<<<dim3(256, 1, 3), blk, 0, stream>>>(zq, zk, zv, 1024);
  }
  rope_split_kern<<<(B_ * S_ * NH_ * 32) / 256, blk, 0, stream>>>(qf, kf, kh, kl, posids, flags);
  vtrans_kern<<<dim3(16, 32), blk, 0, stream>>>(vf, vth, vtl, 1024);
  attn_hl<true><<<512, blk, 0, stream>>>(
      qf, kh, kl, vth, vtl, oh, ol, nullptr, flags, 1024, 1024, 0.125f);
  {
    ZArg zo = {oh, ol, wsph(3), wspl(3), nullptr, x_in, x1, nullptr, nullptr, nullptr, 2048};
    gemm_hl<<<dim3(256, 1, 1), blk, 0, stream>>>(zo, zo, zo, 1024);
  }

  // ---- cross-attention block ----
  rmsnorm_hl_kern<<<T_, blk, 0, stream>>>(x1, cnorm, h2h, h2l);
  {
    ZArg zcq = {h2h, h2l, wsph(4), wspl(4), cqb, nullptr, cqf, nullptr, nullptr, nullptr, 2048};
    ZArg zck = {ench, encl, wsph(5), wspl(5), ckb, nullptr, nullptr, nullptr, ckh, ckl, 1024};
    ZArg zcv = {ench, encl, wsph(6), wspl(6), cvb, nullptr, cvf, nullptr, nullptr, nullptr, 1024};
    gemm_hl<<<dim3(256, 1, 3), blk, 0, stream>>>(zcq, zck, zcv, 1024);
  }
  vtrans_kern<<<dim3(8, 32), blk, 0, stream>>>(cvf, cvth, cvtl, 512);
  attn_hl<false><<<512, blk, 0, stream>>>(
      cqf, ckh, ckl, cvth, cvtl, coh, col, emask, flags, 1024, 512, 0.125f);
  {
    // dual write: x2 (router/rms input) AND out (gemm2 accumulates into it)
    ZArg zco = {coh, col, wsph(7), wspl(7), cob, x1, x2, out, nullptr, nullptr, 2048};
    gemm_hl<<<dim3(256, 1, 1), blk, 0, stream>>>(zco, zco, zco, 1024);
  }

  // ---- MoE block (weight cvt after last wsp use; stream is serial) ----
  cvt_all<<<49152, blk, 0, stream>>>(w1, w3, w2, w1b, w3b, w2b);
  rmsnorm_kern<<<T_, blk, 0, stream>>>(x2, pln, h3b);
  router_kern<<<T_, dim3(64), 0, stream>>>(x2, pln, gatew, topi, topw, counts);
  route_pack_kern<<<1, blk, 0, stream>>>(counts, topi, topw, poff, tm_e, tm_slot,
                                         ntl, perm, pwgt);
  moe_gemm1<<<768, dim3(512), 0, stream>>>(
      h3b, w1b, w3b, ffh, tm_e, tm_slot, ntl, perm);
  moe_gemm2<<<768, blk, 0, stream>>>(
      ffh, w2b, out, tm_e, tm_slot, ntl, perm, pwgt);
}